// Round 1
// baseline (210.735 us; speedup 1.0000x reference)
//
#include <hip/hip_runtime.h>
#include <math.h>

#define NFEAT     512
#define NHID      128
#define NCLASS    70
#define NIDX      10000
#define TM        8
#define NTHREADS  256

__global__ __launch_bounds__(NTHREADS, 3) void hyperada_fused(
    const float* __restrict__ x,
    const float* __restrict__ sf,
    const int*   __restrict__ idx,
    const float* __restrict__ W0,
    const float* __restrict__ W1,
    const float* __restrict__ G1,
    const float* __restrict__ G2,
    const float* __restrict__ GT,
    const float* __restrict__ Wc,
    float* __restrict__ out)
{
    __shared__ __align__(16) float X[2][TM][NFEAT];   // 32 KB raw gathered rows
    __shared__ __align__(16) float H[2][TM][NHID];    // 8 KB  relu layer outputs
    __shared__ __align__(16) float G12[2][TM][NHID];  // 8 KB  gate1|gate2; later fix_inner aliases G12[0]
    __shared__ float scl1[2][TM];
    __shared__ float scl2[TM];
    __shared__ int   rows[TM];

    const int tid = threadIdx.x;

    if (tid < TM) rows[tid] = idx[blockIdx.x * TM + tid];
    __syncthreads();

    // ---- Stage A: gather 2x8 rows of 512 f32 into LDS (coalesced float4) ----
    #pragma unroll
    for (int q = 0; q < 8; ++q) {
        int f = q * NTHREADS + tid;            // 0..2047 float4 slots
        int tensor = f >> 10;                  // 0: x, 1: simple_features
        int m  = (f >> 7) & (TM - 1);
        int k4 = f & 127;
        const float* src = tensor ? sf : x;
        float4 v = reinterpret_cast<const float4*>(src + (size_t)rows[m] * NFEAT)[k4];
        reinterpret_cast<float4*>(&X[tensor][m][0])[k4] = v;
    }
    __syncthreads();

    // ---- row L2 norms (scale folded into stage-B epilogue) ----
    const int wv   = tid >> 6;   // wave id 0..3
    const int lane = tid & 63;
    #pragma unroll
    for (int s = 0; s < 4; ++s) {
        int p = s * 4 + wv;                    // pair 0..15
        int tensor = p >> 3;
        int m = p & (TM - 1);
        const float4* xp = reinterpret_cast<const float4*>(&X[tensor][m][0]);
        float4 a = xp[lane * 2];
        float4 b = xp[lane * 2 + 1];
        float ss = a.x*a.x + a.y*a.y + a.z*a.z + a.w*a.w
                 + b.x*b.x + b.y*b.y + b.z*b.z + b.w*b.w;
        #pragma unroll
        for (int d = 1; d < 64; d <<= 1) ss += __shfl_xor(ss, d, 64);
        if (lane == 0) {
            float n = sqrtf(ss);
            scl1[tensor][m] = (n > 0.f) ? (1.f / n) : 0.f;
        }
    }
    __syncthreads();

    // ---- Stage B: H[t][m][j] = relu(scale * dot512(X[t][m], W[t][j])) ----
    {
        const int tensor = tid >> 7;
        const int j = tid & (NHID - 1);
        const float* Wt = tensor ? W1 : W0;
        const float4* wrow = reinterpret_cast<const float4*>(Wt + (size_t)j * NFEAT);
        float acc[TM];
        #pragma unroll
        for (int m = 0; m < TM; ++m) acc[m] = 0.f;
        #pragma unroll 2
        for (int kc = 0; kc < NFEAT / 4; ++kc) {
            float4 w4 = wrow[kc];
            #pragma unroll
            for (int m = 0; m < TM; ++m) {
                float4 xv = reinterpret_cast<const float4*>(&X[tensor][m][0])[kc]; // wave-broadcast
                acc[m] = fmaf(w4.x, xv.x, acc[m]);
                acc[m] = fmaf(w4.y, xv.y, acc[m]);
                acc[m] = fmaf(w4.z, xv.z, acc[m]);
                acc[m] = fmaf(w4.w, xv.w, acc[m]);
            }
        }
        #pragma unroll
        for (int m = 0; m < TM; ++m)
            H[tensor][m][j] = fmaxf(acc[m] * scl1[tensor][m], 0.f);
    }
    __syncthreads();

    // ---- Stage C: gate1/gate2 = H[t] @ G{1,2}.T ----
    {
        const int tensor = tid >> 7;
        const int j = tid & (NHID - 1);
        const float* Gt = tensor ? G2 : G1;
        const float4* grow = reinterpret_cast<const float4*>(Gt + (size_t)j * NHID);
        float acc[TM];
        #pragma unroll
        for (int m = 0; m < TM; ++m) acc[m] = 0.f;
        #pragma unroll 2
        for (int kc = 0; kc < NHID / 4; ++kc) {
            float4 gv = grow[kc];
            #pragma unroll
            for (int m = 0; m < TM; ++m) {
                float4 hv = reinterpret_cast<const float4*>(&H[tensor][m][0])[kc];
                acc[m] = fmaf(gv.x, hv.x, acc[m]);
                acc[m] = fmaf(gv.y, hv.y, acc[m]);
                acc[m] = fmaf(gv.z, hv.z, acc[m]);
                acc[m] = fmaf(gv.w, hv.w, acc[m]);
            }
        }
        #pragma unroll
        for (int m = 0; m < TM; ++m) G12[tensor][m][j] = acc[m];
    }
    __syncthreads();

    // ---- Stage D: gate = sigmoid([g1,g2] @ GT.T); fix = (1-g)*h0 + g*h1 ----
    float gatev[4];
    const int jD = tid & (NHID - 1);
    const int msetD = tid >> 7;               // 0..1 -> m in {4*msetD .. 4*msetD+3}
    {
        const float4* gtrow = reinterpret_cast<const float4*>(GT + (size_t)jD * (2 * NHID));
        float acc[4];
        #pragma unroll
        for (int mm = 0; mm < 4; ++mm) acc[mm] = 0.f;
        #pragma unroll 2
        for (int kc = 0; kc < (2 * NHID) / 4; ++kc) {
            float4 gv = gtrow[kc];
            int tensor = kc >> 5;             // first 128 cols -> gate1, rest -> gate2
            int kcl = kc & 31;
            #pragma unroll
            for (int mm = 0; mm < 4; ++mm) {
                int m = msetD * 4 + mm;
                float4 cv = reinterpret_cast<const float4*>(&G12[tensor][m][0])[kcl];
                acc[mm] = fmaf(gv.x, cv.x, acc[mm]);
                acc[mm] = fmaf(gv.y, cv.y, acc[mm]);
                acc[mm] = fmaf(gv.z, cv.z, acc[mm]);
                acc[mm] = fmaf(gv.w, cv.w, acc[mm]);
            }
        }
        #pragma unroll
        for (int mm = 0; mm < 4; ++mm)
            gatev[mm] = 1.f / (1.f + __expf(-acc[mm]));
    }
    __syncthreads();   // all G12 reads complete; safe to overwrite with fix_inner

    float* fbuf = &G12[0][0][0];              // fix_inner [TM][NHID] aliases G12[0]
    #pragma unroll
    for (int mm = 0; mm < 4; ++mm) {
        int m = msetD * 4 + mm;
        float g = gatev[mm];
        float f = (1.f - g) * H[0][m][jD] + g * H[1][m][jD];
        fbuf[m * NHID + jD] = f;
    }
    __syncthreads();

    // ---- fix_inner row norms ----
    #pragma unroll
    for (int s = 0; s < 2; ++s) {
        int m = s * 4 + wv;
        float2 v = reinterpret_cast<const float2*>(fbuf + m * NHID)[lane];
        float ss = v.x * v.x + v.y * v.y;
        #pragma unroll
        for (int d = 1; d < 64; d <<= 1) ss += __shfl_xor(ss, d, 64);
        if (lane == 0) {
            float n = sqrtf(ss);
            scl2[m] = (n > 0.f) ? (1.f / n) : 0.f;
        }
    }
    __syncthreads();

    // ---- Stage E: logits = relu(scale2 * fix @ Wc.T); log_softmax; scatter out ----
    {
        const int m  = tid >> 5;              // 8 rows x 32-lane groups
        const int lg = tid & 31;
        const float sc = scl2[m];
        const float4* frow = reinterpret_cast<const float4*>(fbuf + m * NHID);
        float logitv[3];
        #pragma unroll
        for (int ci = 0; ci < 3; ++ci) {
            int c = lg + ci * 32;
            float a = -1e30f;
            if (c < NCLASS) {
                const float4* wr = reinterpret_cast<const float4*>(Wc + (size_t)c * NHID);
                float acc = 0.f;
                #pragma unroll 4
                for (int kc = 0; kc < NHID / 4; ++kc) {
                    float4 w4 = wr[kc];
                    float4 fv = frow[kc];
                    acc = fmaf(w4.x, fv.x, acc);
                    acc = fmaf(w4.y, fv.y, acc);
                    acc = fmaf(w4.z, fv.z, acc);
                    acc = fmaf(w4.w, fv.w, acc);
                }
                a = fmaxf(acc * sc, 0.f);
            }
            logitv[ci] = a;
        }
        float mx = fmaxf(fmaxf(logitv[0], logitv[1]), logitv[2]);
        #pragma unroll
        for (int d = 1; d < 32; d <<= 1) mx = fmaxf(mx, __shfl_xor(mx, d, 32));
        float se = 0.f;
        #pragma unroll
        for (int ci = 0; ci < 3; ++ci) {
            int c = lg + ci * 32;
            if (c < NCLASS) se += __expf(logitv[ci] - mx);
        }
        #pragma unroll
        for (int d = 1; d < 32; d <<= 1) se += __shfl_xor(se, d, 32);
        float lz = mx + __logf(se);
        size_t orow = (size_t)blockIdx.x * TM + m;
        #pragma unroll
        for (int ci = 0; ci < 3; ++ci) {
            int c = lg + ci * 32;
            if (c < NCLASS) out[orow * NCLASS + c] = logitv[ci] - lz;
        }
    }
}

extern "C" void kernel_launch(void* const* d_in, const int* in_sizes, int n_in,
                              void* d_out, int out_size, void* d_ws, size_t ws_size,
                              hipStream_t stream)
{
    const float* x   = (const float*)d_in[0];
    const float* sf  = (const float*)d_in[1];
    const int*   idx = (const int*)d_in[2];
    const float* W0  = (const float*)d_in[3];
    const float* W1  = (const float*)d_in[4];
    const float* G1  = (const float*)d_in[5];
    const float* G2  = (const float*)d_in[6];
    const float* GT  = (const float*)d_in[7];
    const float* Wc  = (const float*)d_in[8];
    float* out = (float*)d_out;

    dim3 grid(NIDX / TM);   // 1250 blocks x 8 rows = 10000 output rows
    hyperada_fused<<<grid, NTHREADS, 0, stream>>>(x, sf, idx, W0, W1, G1, G2, GT, Wc, out);
}

// Round 2
// 59.455 us; speedup vs baseline: 3.5444x; 3.5444x over previous
//
#include <hip/hip_runtime.h>
#include <math.h>

#define NFEAT  512
#define NHID   128
#define NCLASS 70
#define NIDX   10000
#define BM     32
#define NTHREADS 256
#define NBLK   ((NIDX + BM - 1) / BM)   // 313

typedef float  f32x4  __attribute__((ext_vector_type(4)));
typedef __bf16 bf16x8 __attribute__((ext_vector_type(8)));

static __device__ __forceinline__ unsigned short f2bf(float f) {
    unsigned u = __builtin_bit_cast(unsigned, f);
    u += 0x7fffu + ((u >> 16) & 1u);
    return (unsigned short)(u >> 16);
}
static __device__ __forceinline__ float bf2f(unsigned short h) {
    unsigned u = ((unsigned)h) << 16;
    return __builtin_bit_cast(float, u);
}
static __device__ __forceinline__ bf16x8 pack8(float4 a, float4 b) {
    bf16x8 r;
    r[0] = (__bf16)a.x; r[1] = (__bf16)a.y; r[2] = (__bf16)a.z; r[3] = (__bf16)a.w;
    r[4] = (__bf16)b.x; r[5] = (__bf16)b.y; r[6] = (__bf16)b.z; r[7] = (__bf16)b.w;
    return r;
}
static __device__ __forceinline__ bf16x8 gfrag(const float* p) {
    const float4* q = (const float4*)p;
    float4 a = q[0], b = q[1];
    return pack8(a, b);
}
static __device__ __forceinline__ f32x4 MFMA(bf16x8 a, bf16x8 b, f32x4 c) {
    return __builtin_amdgcn_mfma_f32_16x16x32_bf16(a, b, c, 0, 0, 0);
}
// swizzled helpers on a [32][128]-ushort LDS tile (row stride 256 B, T2 XOR swizzle)
static __device__ __forceinline__ bf16x8 ldsA(const unsigned short* base, int row, int bcol) {
    return *(const bf16x8*)((const char*)base + row * 256 + (bcol ^ ((row & 7) << 4)));
}
static __device__ __forceinline__ void ldsW1(unsigned short* base, int row, int col, unsigned short v) {
    *(unsigned short*)((char*)base + row * 256 + ((col * 2) ^ ((row & 7) << 4))) = v;
}
static __device__ __forceinline__ float ldsR1(const unsigned short* base, int row, int col) {
    return bf2f(*(const unsigned short*)((const char*)base + row * 256 + ((col * 2) ^ ((row & 7) << 4))));
}

__global__ __launch_bounds__(NTHREADS) void hyper_fused(
    const float* __restrict__ x, const float* __restrict__ sf,
    const int* __restrict__ idx,
    const float* __restrict__ W0, const float* __restrict__ W1,
    const float* __restrict__ G1, const float* __restrict__ G2,
    const float* __restrict__ GT, const float* __restrict__ Wc,
    float* __restrict__ out)
{
    __shared__ __align__(16) unsigned short Xbuf[2][2][BM][128]; // 32 KB: dbuf x tensor x row x k-chunk
    __shared__ __align__(16) unsigned short Hbuf[2][BM][128];    // 16 KB: relu hidden, both tensors
    __shared__ float scl1[2 * BM];
    __shared__ float scl2[BM];
    __shared__ int   rowsL[BM];

    unsigned short* G12 = &Xbuf[0][0][0][0];      // [2][BM][128] gate1|gate2 (aliases Xbuf[0])
    unsigned short* FIX = &Xbuf[1][0][0][0];      // [BM][128] fix_inner (aliases Xbuf[1])
    float*          LOG = (float*)&Hbuf[0][0][0]; // [BM][80] f32 logits (aliases Hbuf)

    const int tid  = threadIdx.x;
    const int bid  = blockIdx.x;
    const int w    = tid >> 6;
    const int lane = tid & 63;
    const int ln   = lane & 15, lg = lane >> 4;

    if (tid < BM) {
        int gi = bid * BM + tid;
        if (gi > NIDX - 1) gi = NIDX - 1;
        rowsL[tid] = idx[gi];
    }
    __syncthreads();

    // ---- staging slot metadata: 4 slots/thread over [2 tensors][32 rows][16 slots of 8 f32] ----
    const float* sbase[4];
    int stoff[4];
    float part[4] = {0.f, 0.f, 0.f, 0.f};
    #pragma unroll
    for (int i = 0; i < 4; ++i) {
        int s  = tid + i * NTHREADS;
        int r  = s >> 4;              // 0..63 = tensor*32 + m
        int sl = s & 15;
        int t = r >> 5, m = r & 31;
        sbase[i] = (t ? sf : x) + (size_t)rowsL[m] * NFEAT + sl * 8;
        stoff[i] = t * 8192 + m * 256 + ((sl * 16) ^ ((m & 7) << 4));
    }

    const int tB = w >> 1, nh = w & 1;   // wave -> tensor, n-half
    const float* Wt = tB ? W1 : W0;

    const f32x4 zero4 = {0.f, 0.f, 0.f, 0.f};
    f32x4 accB[2][4];
    #pragma unroll
    for (int a = 0; a < 2; ++a)
        #pragma unroll
        for (int b = 0; b < 4; ++b) accB[a][b] = zero4;

    auto STAGE = [&](int c, int bsel) {
        char* dst = (char*)&Xbuf[bsel][0][0][0];
        #pragma unroll
        for (int i = 0; i < 4; ++i) {
            const float4* q = (const float4*)(sbase[i] + c * 128);
            float4 a = q[0], b = q[1];
            part[i] += a.x*a.x + a.y*a.y + a.z*a.z + a.w*a.w
                     + b.x*b.x + b.y*b.y + b.z*b.z + b.w*b.w;
            *(bf16x8*)(dst + stoff[i]) = pack8(a, b);
        }
    };
    auto CB = [&](int c, int bsel) {
        const unsigned short* Xb = &Xbuf[bsel][tB][0][0];
        #pragma unroll
        for (int ks = 0; ks < 4; ++ks) {
            bf16x8 a0 = ldsA(Xb, ln,      ks * 64 + lg * 16);
            bf16x8 a1 = ldsA(Xb, 16 + ln, ks * 64 + lg * 16);
            #pragma unroll
            for (int nt = 0; nt < 4; ++nt) {
                int n = nh * 64 + nt * 16 + ln;
                bf16x8 bf = gfrag(Wt + (size_t)n * NFEAT + c * 128 + ks * 32 + lg * 8);
                accB[0][nt] = MFMA(a0, bf, accB[0][nt]);
                accB[1][nt] = MFMA(a1, bf, accB[1][nt]);
            }
        }
    };

    // ---- stage B: X @ W^T with K-chunked double-buffered staging ----
    STAGE(0, 0);
    __syncthreads();
    for (int c = 0; c < 4; ++c) {
        if (c < 3) STAGE(c + 1, (c + 1) & 1);
        CB(c, c & 1);
        __syncthreads();
    }

    // ---- row sumsq reduce -> scl1 (norm folded into epilogue) ----
    #pragma unroll
    for (int i = 0; i < 4; ++i) {
        float s = part[i];
        s += __shfl_xor(s, 1); s += __shfl_xor(s, 2);
        s += __shfl_xor(s, 4); s += __shfl_xor(s, 8);
        part[i] = s;
    }
    if ((tid & 15) == 0) {
        #pragma unroll
        for (int i = 0; i < 4; ++i) {
            int r = (tid >> 4) + 16 * i;
            scl1[r] = (part[i] > 0.f) ? (1.f / sqrtf(part[i])) : 0.f;
        }
    }
    __syncthreads();

    // ---- H = relu(scl1 * acc) -> bf16 LDS ----
    {
        unsigned short* Hb = &Hbuf[tB][0][0];
        #pragma unroll
        for (int mt = 0; mt < 2; ++mt)
            #pragma unroll
            for (int nt = 0; nt < 4; ++nt)
                #pragma unroll
                for (int rg = 0; rg < 4; ++rg) {
                    int m = mt * 16 + lg * 4 + rg;
                    float v = accB[mt][nt][rg] * scl1[tB * 32 + m];
                    ldsW1(Hb, m, nh * 64 + nt * 16 + ln, f2bf(fmaxf(v, 0.f)));
                }
    }
    __syncthreads();

    // ---- stage C: gate1/gate2 = H[t] @ G{1,2}^T ----
    {
        f32x4 accC[2][4];
        #pragma unroll
        for (int a = 0; a < 2; ++a)
            #pragma unroll
            for (int b = 0; b < 4; ++b) accC[a][b] = zero4;
        const float* Gt = tB ? G2 : G1;
        const unsigned short* Hs = &Hbuf[tB][0][0];
        #pragma unroll
        for (int ks = 0; ks < 4; ++ks) {
            bf16x8 a0 = ldsA(Hs, ln,      ks * 64 + lg * 16);
            bf16x8 a1 = ldsA(Hs, 16 + ln, ks * 64 + lg * 16);
            #pragma unroll
            for (int nt = 0; nt < 4; ++nt) {
                int n = nh * 64 + nt * 16 + ln;
                bf16x8 bf = gfrag(Gt + (size_t)n * NHID + ks * 32 + lg * 8);
                accC[0][nt] = MFMA(a0, bf, accC[0][nt]);
                accC[1][nt] = MFMA(a1, bf, accC[1][nt]);
            }
        }
        unsigned short* Gd = G12 + tB * (BM * 128);
        #pragma unroll
        for (int mt = 0; mt < 2; ++mt)
            #pragma unroll
            for (int nt = 0; nt < 4; ++nt)
                #pragma unroll
                for (int rg = 0; rg < 4; ++rg) {
                    int m = mt * 16 + lg * 4 + rg;
                    ldsW1(Gd, m, nh * 64 + nt * 16 + ln, f2bf(accC[mt][nt][rg]));
                }
    }
    __syncthreads();

    // ---- stage D: gate = sigmoid([g1,g2] @ GT^T); fix = (1-g)H0 + g H1 ----
    {
        f32x4 accD[2][2];
        accD[0][0] = zero4; accD[0][1] = zero4; accD[1][0] = zero4; accD[1][1] = zero4;
        #pragma unroll
        for (int ks = 0; ks < 8; ++ks) {
            const unsigned short* As = G12 + (ks >> 2) * (BM * 128);
            int kk = ks & 3;
            bf16x8 a0 = ldsA(As, ln,      kk * 64 + lg * 16);
            bf16x8 a1 = ldsA(As, 16 + ln, kk * 64 + lg * 16);
            #pragma unroll
            for (int ntl = 0; ntl < 2; ++ntl) {
                int n = w * 32 + ntl * 16 + ln;
                bf16x8 bf = gfrag(GT + (size_t)n * (2 * NHID) + ks * 32 + lg * 8);
                accD[0][ntl] = MFMA(a0, bf, accD[0][ntl]);
                accD[1][ntl] = MFMA(a1, bf, accD[1][ntl]);
            }
        }
        #pragma unroll
        for (int mt = 0; mt < 2; ++mt)
            #pragma unroll
            for (int ntl = 0; ntl < 2; ++ntl)
                #pragma unroll
                for (int rg = 0; rg < 4; ++rg) {
                    int m  = mt * 16 + lg * 4 + rg;
                    int cc = w * 32 + ntl * 16 + ln;
                    float g  = 1.f / (1.f + __expf(-accD[mt][ntl][rg]));
                    float h0 = ldsR1(&Hbuf[0][0][0], m, cc);
                    float h1 = ldsR1(&Hbuf[1][0][0], m, cc);
                    ldsW1(FIX, m, cc, f2bf((1.f - g) * h0 + g * h1));
                }
    }
    __syncthreads();

    // ---- fix_inner row norms -> scl2 ----
    {
        int r = tid >> 3, sl = tid & 7;
        const char* base = (const char*)FIX + r * 256;
        bf16x8 v0 = *(const bf16x8*)(base + ((sl * 32)      ^ ((r & 7) << 4)));
        bf16x8 v1 = *(const bf16x8*)(base + ((sl * 32 + 16) ^ ((r & 7) << 4)));
        float ss = 0.f;
        #pragma unroll
        for (int j = 0; j < 8; ++j) {
            float f0 = (float)v0[j]; ss += f0 * f0;
            float f1 = (float)v1[j]; ss += f1 * f1;
        }
        ss += __shfl_xor(ss, 1); ss += __shfl_xor(ss, 2); ss += __shfl_xor(ss, 4);
        if (sl == 0) scl2[r] = (ss > 0.f) ? (1.f / sqrtf(ss)) : 0.f;
    }
    __syncthreads();

    // ---- stage E: logits = relu(scl2 * fix @ Wc^T) -> LOG (cols >=70 get -1e30) ----
    {
        bf16x8 bfz;
        #pragma unroll
        for (int j = 0; j < 8; ++j) bfz[j] = (__bf16)0.f;
        auto DO_NT = [&](int nt) {
            f32x4 acc0 = zero4, acc1 = zero4;
            int cc = nt * 16 + ln;
            #pragma unroll
            for (int ks = 0; ks < 4; ++ks) {
                bf16x8 a0 = ldsA(FIX, ln,      ks * 64 + lg * 16);
                bf16x8 a1 = ldsA(FIX, 16 + ln, ks * 64 + lg * 16);
                bf16x8 bf = (cc < NCLASS) ? gfrag(Wc + (size_t)cc * NHID + ks * 32 + lg * 8) : bfz;
                acc0 = MFMA(a0, bf, acc0);
                acc1 = MFMA(a1, bf, acc1);
            }
            #pragma unroll
            for (int mt = 0; mt < 2; ++mt)
                #pragma unroll
                for (int rg = 0; rg < 4; ++rg) {
                    int m = mt * 16 + lg * 4 + rg;
                    float av = (mt == 0) ? acc0[rg] : acc1[rg];
                    float v = fmaxf(av * scl2[m], 0.f);
                    if (cc >= NCLASS) v = -1e30f;
                    LOG[m * 80 + nt * 16 + ln] = v;
                }
        };
        DO_NT(w);
        if (w == 0) DO_NT(4);
    }
    __syncthreads();

    // ---- log_softmax + store ----
    {
        int hw = tid >> 5, l32 = tid & 31;
        #pragma unroll
        for (int j = 0; j < 4; ++j) {
            int r = hw * 4 + j;
            float v0 = LOG[r * 80 + l32];
            float v1 = LOG[r * 80 + 32 + l32];
            float v2 = (l32 < 16) ? LOG[r * 80 + 64 + l32] : -1e30f;
            float mx = fmaxf(fmaxf(v0, v1), v2);
            #pragma unroll
            for (int d = 1; d < 32; d <<= 1) mx = fmaxf(mx, __shfl_xor(mx, d, 32));
            float se = __expf(v0 - mx) + __expf(v1 - mx) + ((l32 < 16) ? __expf(v2 - mx) : 0.f);
            #pragma unroll
            for (int d = 1; d < 32; d <<= 1) se += __shfl_xor(se, d, 32);
            float lz = mx + __logf(se);
            int orow = bid * BM + r;
            if (orow < NIDX) {
                out[(size_t)orow * NCLASS + l32] = v0 - lz;
                if (l32 + 32 < NCLASS) out[(size_t)orow * NCLASS + 32 + l32] = v1 - lz;
                if (l32 + 64 < NCLASS) out[(size_t)orow * NCLASS + 64 + l32] = v2 - lz;
            }
        }
    }
}

extern "C" void kernel_launch(void* const* d_in, const int* in_sizes, int n_in,
                              void* d_out, int out_size, void* d_ws, size_t ws_size,
                              hipStream_t stream)
{
    const float* x   = (const float*)d_in[0];
    const float* sf  = (const float*)d_in[1];
    const int*   idx = (const int*)d_in[2];
    const float* W0  = (const float*)d_in[3];
    const float* W1  = (const float*)d_in[4];
    const float* G1  = (const float*)d_in[5];
    const float* G2  = (const float*)d_in[6];
    const float* GT  = (const float*)d_in[7];
    const float* Wc  = (const float*)d_in[8];
    float* out = (float*)d_out;

    hyper_fused<<<dim3(NBLK), dim3(NTHREADS), 0, stream>>>(x, sf, idx, W0, W1, G1, G2, GT, Wc, out);
}

// Round 3
// 52.927 us; speedup vs baseline: 3.9816x; 1.1233x over previous
//
#include <hip/hip_runtime.h>
#include <math.h>

#define NFEAT    512
#define NHID     128
#define NCLASS   70
#define NIDX     10000
#define BM       16
#define NTHREADS 512
#define NBLK     (NIDX / BM)   // 625 exactly

typedef float  f32x4  __attribute__((ext_vector_type(4)));
typedef __bf16 bf16x8 __attribute__((ext_vector_type(8)));

static __device__ __forceinline__ unsigned short f2bf(float f) {
    unsigned u = __builtin_bit_cast(unsigned, f);
    u += 0x7fffu + ((u >> 16) & 1u);
    return (unsigned short)(u >> 16);
}
static __device__ __forceinline__ float bf2f(unsigned short h) {
    unsigned u = ((unsigned)h) << 16;
    return __builtin_bit_cast(float, u);
}
static __device__ __forceinline__ bf16x8 pack8(float4 a, float4 b) {
    bf16x8 r;
    r[0] = (__bf16)a.x; r[1] = (__bf16)a.y; r[2] = (__bf16)a.z; r[3] = (__bf16)a.w;
    r[4] = (__bf16)b.x; r[5] = (__bf16)b.y; r[6] = (__bf16)b.z; r[7] = (__bf16)b.w;
    return r;
}
static __device__ __forceinline__ f32x4 MFMA(bf16x8 a, bf16x8 b, f32x4 c) {
    return __builtin_amdgcn_mfma_f32_16x16x32_bf16(a, b, c, 0, 0, 0);
}
// swizzled LDS helpers; rstride in bytes (compile-time const at call sites)
static __device__ __forceinline__ bf16x8 ldsAx(const unsigned short* base, int row, int colb, int rstride) {
    return *(const bf16x8*)((const char*)base + row * rstride + (colb ^ ((row & 7) << 4)));
}
static __device__ __forceinline__ void ldsW1(unsigned short* base, int row, int col, unsigned short v) {
    *(unsigned short*)((char*)base + row * 256 + ((col * 2) ^ ((row & 7) << 4))) = v;
}
static __device__ __forceinline__ float ldsR1(const unsigned short* base, int row, int col) {
    return bf2f(*(const unsigned short*)((const char*)base + row * 256 + ((col * 2) ^ ((row & 7) << 4))));
}

// B-fragment loader: bf16 direct (PRE) or f32+convert (fallback)
template<bool PRE>
static __device__ __forceinline__ bf16x8 bfrag(const void* p, size_t off) {
    if constexpr (PRE) {
        return *(const bf16x8*)((const unsigned short*)p + off);
    } else {
        const float4* q = (const float4*)((const float*)p + off);
        return pack8(q[0], q[1]);
    }
}

// ---- prep: convert all weights f32 -> bf16 into d_ws (row-major, same order) ----
// float4 segment boundaries: W0 16384, W1 16384, G1 4096, G2 4096, GT 8192, Wc 2240
__global__ void prep_weights(const float* __restrict__ W0, const float* __restrict__ W1,
                             const float* __restrict__ G1, const float* __restrict__ G2,
                             const float* __restrict__ GT, const float* __restrict__ Wc,
                             unsigned short* __restrict__ ws) {
    int i4 = blockIdx.x * 256 + threadIdx.x;
    if (i4 >= 51392) return;
    const float* src; int base4;
    if      (i4 < 16384) { src = W0; base4 = 0; }
    else if (i4 < 32768) { src = W1; base4 = 16384; }
    else if (i4 < 36864) { src = G1; base4 = 32768; }
    else if (i4 < 40960) { src = G2; base4 = 36864; }
    else if (i4 < 49152) { src = GT; base4 = 40960; }
    else                 { src = Wc; base4 = 49152; }
    float4 v = ((const float4*)src)[i4 - base4];
    ushort4 o;
    o.x = f2bf(v.x); o.y = f2bf(v.y); o.z = f2bf(v.z); o.w = f2bf(v.w);
    ((ushort4*)ws)[i4] = o;
}

template<bool PRE>
__global__ __launch_bounds__(NTHREADS) void hyper_fused(
    const float* __restrict__ x, const float* __restrict__ sf,
    const int* __restrict__ idx,
    const float* __restrict__ W0, const float* __restrict__ W1,
    const float* __restrict__ G1, const float* __restrict__ G2,
    const float* __restrict__ GT, const float* __restrict__ Wc,
    const unsigned short* __restrict__ wsb,
    float* __restrict__ out)
{
    __shared__ __align__(16) unsigned short Xbuf[2][BM][NFEAT]; // 32 KB bf16 gathered rows
    __shared__ __align__(16) unsigned short Hbuf[2][BM][NHID];  // 8 KB relu hidden
    __shared__ float scl1[32];
    __shared__ float scl2[BM];
    __shared__ int   rowsL[BM];

    // stage C/D/E scratch aliases into Xbuf (X dead after stage B)
    unsigned short* G12 = &Xbuf[0][0][0];          // [2][16][128] bf16, 8 KB @ 0
    unsigned short* FIX = &Xbuf[0][0][0] + 4096;   // [16][128]   bf16, 4 KB @ 8 KB
    float*          LOG = (float*)(&Xbuf[0][0][0] + 6144); // [16][80] f32, 5 KB @ 12 KB

    const void* W0p = PRE ? (const void*)wsb            : (const void*)W0;
    const void* W1p = PRE ? (const void*)(wsb + 65536)  : (const void*)W1;
    const void* G1p = PRE ? (const void*)(wsb + 131072) : (const void*)G1;
    const void* G2p = PRE ? (const void*)(wsb + 147456) : (const void*)G2;
    const void* GTp = PRE ? (const void*)(wsb + 163840) : (const void*)GT;
    const void* Wcp = PRE ? (const void*)(wsb + 196608) : (const void*)Wc;

    const int tid  = threadIdx.x;
    const int bid  = blockIdx.x;
    const int w    = tid >> 6;          // wave 0..7
    const int lane = tid & 63;
    const int ln   = lane & 15, lg = lane >> 4;

    if (tid < BM) rowsL[tid] = idx[bid * BM + tid];   // 625*16 == 10000, no clamp needed
    __syncthreads();

    // ---- gather ALL of X up front: 2048 slots of 8 f32; 4 slots (128 B) per thread ----
    // slot s: r = s>>6 in [0,32) = t*16+m, sl = s&63. wave w, group i stages row r = w+8i fully coalesced.
    float part[4];
    {
        char* xb = (char*)&Xbuf[0][0][0];
        #pragma unroll
        for (int i = 0; i < 4; ++i) {
            int s  = tid + i * NTHREADS;
            int r  = s >> 6, sl = s & 63;
            int t = r >> 4, m = r & 15;
            const float4* q = (const float4*)((t ? sf : x) + (size_t)rowsL[m] * NFEAT + sl * 8);
            float4 a = q[0], b = q[1];
            part[i] = a.x*a.x + a.y*a.y + a.z*a.z + a.w*a.w
                    + b.x*b.x + b.y*b.y + b.z*b.z + b.w*b.w;
            int soff = t * 16384 + m * 1024 + ((sl * 16) ^ ((m & 7) << 4));
            *(bf16x8*)(xb + soff) = pack8(a, b);
        }
        // wave-wide sumsq reduce: wave w group i owns row w+8i entirely
        #pragma unroll
        for (int i = 0; i < 4; ++i) {
            float s = part[i];
            #pragma unroll
            for (int d = 1; d < 64; d <<= 1) s += __shfl_xor(s, d);
            if (lane == 0) scl1[w + 8 * i] = (s > 0.f) ? (1.f / sqrtf(s)) : 0.f;
        }
    }
    __syncthreads();

    const int tB = w >> 2, nq = w & 3;  // wave -> tensor, N-quarter (32 cols)
    const f32x4 zero4 = {0.f, 0.f, 0.f, 0.f};

    // ---- stage B: H[t] = relu(scl1 * X[t] @ W[t]^T), K=512 straight-line ----
    {
        const void* Wp = tB ? W1p : W0p;
        f32x4 accB[2] = {zero4, zero4};
        const unsigned short* Xb = (const unsigned short*)((const char*)&Xbuf[0][0][0] + tB * 16384);
        #pragma unroll
        for (int kc = 0; kc < 16; ++kc) {
            bf16x8 a = ldsAx(Xb, ln, kc * 64 + lg * 16, 1024);
            #pragma unroll
            for (int nt = 0; nt < 2; ++nt) {
                int n = nq * 32 + nt * 16 + ln;
                bf16x8 b = bfrag<PRE>(Wp, (size_t)n * NFEAT + kc * 32 + lg * 8);
                accB[nt] = MFMA(a, b, accB[nt]);
            }
        }
        unsigned short* Hb = &Hbuf[tB][0][0];
        #pragma unroll
        for (int nt = 0; nt < 2; ++nt)
            #pragma unroll
            for (int rg = 0; rg < 4; ++rg) {
                int m = lg * 4 + rg;
                float v = accB[nt][rg] * scl1[tB * 16 + m];
                ldsW1(Hb, m, nq * 32 + nt * 16 + ln, f2bf(fmaxf(v, 0.f)));
            }
    }
    __syncthreads();

    // ---- stage C: gate1/gate2 = H[t] @ G{1,2}^T, K=128 ----
    {
        const void* Gp = tB ? G2p : G1p;
        const unsigned short* Hs = &Hbuf[tB][0][0];
        f32x4 accC[2] = {zero4, zero4};
        #pragma unroll
        for (int kc = 0; kc < 4; ++kc) {
            bf16x8 a = ldsAx(Hs, ln, kc * 64 + lg * 16, 256);
            #pragma unroll
            for (int nt = 0; nt < 2; ++nt) {
                int n = nq * 32 + nt * 16 + ln;
                bf16x8 b = bfrag<PRE>(Gp, (size_t)n * NHID + kc * 32 + lg * 8);
                accC[nt] = MFMA(a, b, accC[nt]);
            }
        }
        unsigned short* Gd = G12 + tB * 2048;   // [16][128] per tensor
        #pragma unroll
        for (int nt = 0; nt < 2; ++nt)
            #pragma unroll
            for (int rg = 0; rg < 4; ++rg) {
                int m = lg * 4 + rg;
                ldsW1(Gd, m, nq * 32 + nt * 16 + ln, f2bf(accC[nt][rg]));
            }
    }
    __syncthreads();

    // ---- stage D: gate = sigmoid([g1,g2] @ GT^T); fix = (1-g)H0 + g H1, K=256 ----
    {
        f32x4 accD = zero4;
        const int n = w * 16 + ln;              // 8 waves x 16 cols = 128
        #pragma unroll
        for (int kc = 0; kc < 8; ++kc) {
            const unsigned short* As = G12 + (kc >> 2) * 2048;
            bf16x8 a = ldsAx(As, ln, (kc & 3) * 64 + lg * 16, 256);
            bf16x8 b = bfrag<PRE>(GTp, (size_t)n * (2 * NHID) + kc * 32 + lg * 8);
            accD = MFMA(a, b, accD);
        }
        #pragma unroll
        for (int rg = 0; rg < 4; ++rg) {
            int m = lg * 4 + rg;
            float g  = 1.f / (1.f + __expf(-accD[rg]));
            float h0 = ldsR1(&Hbuf[0][0][0], m, n);
            float h1 = ldsR1(&Hbuf[1][0][0], m, n);
            ldsW1(FIX, m, n, f2bf((1.f - g) * h0 + g * h1));
        }
    }
    __syncthreads();

    // ---- fix_inner row norms -> scl2 (first 256 threads) ----
    if (tid < 256) {
        int r = tid >> 4, sl = tid & 15;
        bf16x8 v = ldsAx(FIX, r, sl * 16, 256);
        float ss = 0.f;
        #pragma unroll
        for (int j = 0; j < 8; ++j) { float f = (float)v[j]; ss += f * f; }
        ss += __shfl_xor(ss, 1); ss += __shfl_xor(ss, 2);
        ss += __shfl_xor(ss, 4); ss += __shfl_xor(ss, 8);
        if (sl == 0) scl2[r] = (ss > 0.f) ? (1.f / sqrtf(ss)) : 0.f;
    }
    __syncthreads();

    // ---- stage E: logits = relu(scl2 * fix @ Wc^T), cols>=NCLASS -> -inf pad ----
    if (w < 5) {
        const int cc = w * 16 + ln;             // 0..79
        bf16x8 bfz;
        #pragma unroll
        for (int j = 0; j < 8; ++j) bfz[j] = (__bf16)0.f;
        f32x4 accE = zero4;
        #pragma unroll
        for (int kc = 0; kc < 4; ++kc) {
            bf16x8 a = ldsAx(FIX, ln, kc * 64 + lg * 16, 256);
            bf16x8 b = (cc < NCLASS) ? bfrag<PRE>(Wcp, (size_t)cc * NHID + kc * 32 + lg * 8) : bfz;
            accE = MFMA(a, b, accE);
        }
        #pragma unroll
        for (int rg = 0; rg < 4; ++rg) {
            int m = lg * 4 + rg;
            float v = fmaxf(accE[rg] * scl2[m], 0.f);
            LOG[m * 80 + cc] = (cc < NCLASS) ? v : -1e30f;
        }
    }
    __syncthreads();

    // ---- log_softmax + store: one 32-lane group per row ----
    {
        const int r = tid >> 5, l32 = tid & 31;  // 16 rows exactly
        float v0 = LOG[r * 80 + l32];
        float v1 = LOG[r * 80 + 32 + l32];
        float v2 = (l32 < 16) ? LOG[r * 80 + 64 + l32] : -1e30f;
        float mx = fmaxf(fmaxf(v0, v1), v2);
        #pragma unroll
        for (int d = 1; d < 32; d <<= 1) mx = fmaxf(mx, __shfl_xor(mx, d, 32));
        float se = __expf(v0 - mx) + __expf(v1 - mx) + ((l32 < 16) ? __expf(v2 - mx) : 0.f);
        #pragma unroll
        for (int d = 1; d < 32; d <<= 1) se += __shfl_xor(se, d, 32);
        float lz = mx + __logf(se);
        size_t orow = (size_t)bid * BM + r;
        out[orow * NCLASS + l32] = v0 - lz;
        if (l32 + 32 < NCLASS) out[orow * NCLASS + 32 + l32] = v1 - lz;
        if (l32 + 64 < NCLASS) out[orow * NCLASS + 64 + l32] = v2 - lz;
    }
}

extern "C" void kernel_launch(void* const* d_in, const int* in_sizes, int n_in,
                              void* d_out, int out_size, void* d_ws, size_t ws_size,
                              hipStream_t stream)
{
    const float* x   = (const float*)d_in[0];
    const float* sf  = (const float*)d_in[1];
    const int*   idx = (const int*)d_in[2];
    const float* W0  = (const float*)d_in[3];
    const float* W1  = (const float*)d_in[4];
    const float* G1  = (const float*)d_in[5];
    const float* G2  = (const float*)d_in[6];
    const float* GT  = (const float*)d_in[7];
    const float* Wc  = (const float*)d_in[8];
    float* out = (float*)d_out;

    const size_t need = 205568ull * 2;   // all weights as bf16
    if (ws_size >= need) {
        unsigned short* ws = (unsigned short*)d_ws;
        prep_weights<<<dim3(201), dim3(256), 0, stream>>>(W0, W1, G1, G2, GT, Wc, ws);
        hyper_fused<true><<<dim3(NBLK), dim3(NTHREADS), 0, stream>>>(
            x, sf, idx, W0, W1, G1, G2, GT, Wc, ws, out);
    } else {
        hyper_fused<false><<<dim3(NBLK), dim3(NTHREADS), 0, stream>>>(
            x, sf, idx, W0, W1, G1, G2, GT, Wc, nullptr, out);
    }
}